// Round 3
// baseline (2112.506 us; speedup 1.0000x reference)
//
#include <hip/hip_runtime.h>
#include <math.h>

// N=100000 nodes, E=6400000 edges, avg degree 64.
// out[n] = [cos(th_n), sin(th_n), w_n],  w_n = S_y / max(||S||, eps),
//   S_x = cos(th)*C + sin(th)*S,  S_y = cos(th)*S - sin(th)*C,
//   C_n = sum_{e:dst=n} cos(x[src_e]),  S_n = sum_{e:dst=n} sin(x[src_e]).
// R2 post-mortem: LDS-privatized scan was latency-chain-bound (VALUBusy 9%,
// HBM 3%): 4 serialized esrc->cst->atomic chains per iter behind vmcnt(0),
// 16 waves/CU. R3: branchless inner loop (unconditional int4 edst+esrc,
// gather redirected to cst[0] on miss, atomics redirected to per-lane dummy
// LDS slots), NPART=32 -> 25.25KB LDS -> 4 blocks/CU, grid 1024 -> 32
// waves/CU, and slice->XCD alignment (blk%8 == s%8) keeps rescans in L2.

#define EPS 1e-12f
#define NPART 32
#define NSLICE 32      // grid = NPART*NSLICE = 1024 = 4 blocks/CU
#define RMAX 3125      // ceil(100000/32)
#define BLK 512

// ---------------- fast path ----------------

__global__ void build_cs_kernel(const float* __restrict__ x,
                                float2* __restrict__ cst, int N) {
    int i = blockIdx.x * blockDim.x + threadIdx.x;
    if (i < N) {
        float sn, cs;
        __sincosf(x[i], &sn, &cs);
        cst[i] = make_float2(cs, sn);
    }
}

__global__ __launch_bounds__(BLK, 8) void scatter_lds_kernel(
        const float2* __restrict__ cst,
        const int* __restrict__ esrc,
        const int* __restrict__ edst,
        float* __restrict__ buf,       // [NPART*NSLICE][2*R]
        int E, int R) {
    __shared__ float lacc[2 * RMAX + 64];  // [0,R)=C, [R,2R)=S, [2R,2R+64)=trash
    const int p = blockIdx.x / NSLICE;
    const int s = blockIdx.x % NSLICE;     // XCD = blk%8 = s%8 -> slice L2 locality
    const int pBeg = p * R;

    for (int k = threadIdx.x; k < 2 * RMAX + 64; k += BLK) lacc[k] = 0.0f;
    __syncthreads();

    const int per = (E + NSLICE - 1) / NSLICE;
    const int beg = s * per;
    const int end = min(beg + per, E);
    const int dummy = 2 * R + (threadIdx.x & 63);  // per-lane trash slot

    int tail_beg = beg;
    if ((beg & 3) == 0) {
        const int endv = beg + ((end - beg) & ~3);
        tail_beg = endv;
        for (int i = beg + threadIdx.x * 4; i < endv; i += BLK * 4) {
            const int4 d4 = *(const int4*)&edst[i];
            const int4 s4 = *(const int4*)&esrc[i];
            const unsigned dl0 = (unsigned)(d4.x - pBeg);
            const unsigned dl1 = (unsigned)(d4.y - pBeg);
            const unsigned dl2 = (unsigned)(d4.z - pBeg);
            const unsigned dl3 = (unsigned)(d4.w - pBeg);
            const bool h0 = dl0 < (unsigned)R;
            const bool h1 = dl1 < (unsigned)R;
            const bool h2 = dl2 < (unsigned)R;
            const bool h3 = dl3 < (unsigned)R;
            // miss lanes collapse to cst[0]: one broadcast line per wave
            const float2 v0 = cst[h0 ? s4.x : 0];
            const float2 v1 = cst[h1 ? s4.y : 0];
            const float2 v2 = cst[h2 ? s4.z : 0];
            const float2 v3 = cst[h3 ? s4.w : 0];
            // miss lanes redirected to distinct trash slots (never read back)
            atomicAdd(&lacc[h0 ? (int)dl0 : dummy], v0.x);
            atomicAdd(&lacc[h0 ? (int)(dl0 + R) : dummy], v0.y);
            atomicAdd(&lacc[h1 ? (int)dl1 : dummy], v1.x);
            atomicAdd(&lacc[h1 ? (int)(dl1 + R) : dummy], v1.y);
            atomicAdd(&lacc[h2 ? (int)dl2 : dummy], v2.x);
            atomicAdd(&lacc[h2 ? (int)(dl2 + R) : dummy], v2.y);
            atomicAdd(&lacc[h3 ? (int)dl3 : dummy], v3.x);
            atomicAdd(&lacc[h3 ? (int)(dl3 + R) : dummy], v3.y);
        }
    }
    for (int i = tail_beg + threadIdx.x; i < end; i += BLK) {
        unsigned dl = (unsigned)(edst[i] - pBeg);
        if (dl < (unsigned)R) {
            float2 v = cst[esrc[i]];
            atomicAdd(&lacc[dl], v.x);
            atomicAdd(&lacc[dl + R], v.y);
        }
    }

    __syncthreads();
    float* dst = buf + (size_t)blockIdx.x * (2 * R);
    for (int k = threadIdx.x; k < 2 * R; k += BLK) dst[k] = lacc[k];
}

__global__ void reduce_node_kernel(const float* __restrict__ theta,
                                   const float* __restrict__ buf,
                                   float* __restrict__ out, int N, int R) {
    int n = blockIdx.x * blockDim.x + threadIdx.x;
    if (n >= N) return;
    int p = n / R, j = n - p * R;
    float C = 0.0f, Sv = 0.0f;
    size_t base = (size_t)p * NSLICE * 2 * R + j;
    #pragma unroll 8
    for (int s = 0; s < NSLICE; ++s) {
        const float* b = buf + base + (size_t)s * 2 * R;
        C  += b[0];
        Sv += b[R];
    }
    float sn, cs;
    __sincosf(theta[n], &sn, &cs);
    float nrm = fmaxf(sqrtf(C * C + Sv * Sv), EPS);
    out[3 * n + 0] = cs;
    out[3 * n + 1] = sn;
    out[3 * n + 2] = (cs * Sv - sn * C) / nrm;
}

// ---------------- fallback path (R1: global atomics) ----------------

__global__ void zero_kernel(float* __restrict__ p, int n) {
    int i = blockIdx.x * blockDim.x + threadIdx.x;
    if (i < n) p[i] = 0.0f;
}

__global__ void edge_atomic_kernel(const float* __restrict__ x,
                                   const float* __restrict__ theta,
                                   const int* __restrict__ esrc,
                                   const int* __restrict__ edst,
                                   float* __restrict__ acc, int E) {
    int i = blockIdx.x * blockDim.x + threadIdx.x;
    if (i >= E) return;
    int s = esrc[i], d = edst[i];
    float dt = x[s] - theta[d];
    float sn, cs;
    __sincosf(dt, &sn, &cs);
    atomicAdd(&acc[2 * d], cs);
    atomicAdd(&acc[2 * d + 1], sn);
}

__global__ void node_atomic_kernel(const float* __restrict__ theta,
                                   const float* __restrict__ acc,
                                   float* __restrict__ out, int N) {
    int n = blockIdx.x * blockDim.x + threadIdx.x;
    if (n >= N) return;
    float sn, cs;
    __sincosf(theta[n], &sn, &cs);
    float sx = acc[2 * n], sy = acc[2 * n + 1];
    float nrm = fmaxf(sqrtf(sx * sx + sy * sy), EPS);
    out[3 * n + 0] = cs;
    out[3 * n + 1] = sn;
    out[3 * n + 2] = sy / nrm;
}

extern "C" void kernel_launch(void* const* d_in, const int* in_sizes, int n_in,
                              void* d_out, int out_size, void* d_ws, size_t ws_size,
                              hipStream_t stream) {
    const float* x     = (const float*)d_in[0];
    const float* theta = (const float*)d_in[1];
    const int*   esrc  = (const int*)d_in[2];
    const int*   edst  = (const int*)d_in[3];
    float*       out   = (float*)d_out;

    int N = in_sizes[0];
    int E = in_sizes[2];
    int R = (N + NPART - 1) / NPART;

    size_t buf_bytes = (size_t)NPART * NSLICE * 2 * R * sizeof(float);
    size_t cst_bytes = (size_t)N * sizeof(float2);

    if (R <= RMAX && ws_size >= buf_bytes + cst_bytes) {
        float*  buf = (float*)d_ws;
        float2* cst = (float2*)((char*)d_ws + buf_bytes);
        build_cs_kernel<<<(N + 255) / 256, 256, 0, stream>>>(x, cst, N);
        scatter_lds_kernel<<<NPART * NSLICE, BLK, 0, stream>>>(cst, esrc, edst, buf, E, R);
        reduce_node_kernel<<<(N + 255) / 256, 256, 0, stream>>>(theta, buf, out, N, R);
    } else {
        float* acc = (float*)d_ws;
        const int B = 256;
        zero_kernel<<<(2 * N + B - 1) / B, B, 0, stream>>>(acc, 2 * N);
        edge_atomic_kernel<<<(E + B - 1) / B, B, 0, stream>>>(x, theta, esrc, edst, acc, E);
        node_atomic_kernel<<<(N + B - 1) / B, B, 0, stream>>>(theta, acc, out, N);
    }
}

// Round 4
// 199.203 us; speedup vs baseline: 10.6048x; 10.6048x over previous
//
#include <hip/hip_runtime.h>
#include <math.h>

// N=100000 nodes, E=6400000 edges, avg degree 64.
// out[n] = [cos(th_n), sin(th_n), w_n],  w_n = S_y / max(||S||, eps),
//   S_x = cos(th)*C + sin(th)*S,  S_y = cos(th)*S - sin(th)*C,
//   C_n = sum_{e:dst=n} cos(x[src_e]),  S_n = sum_{e:dst=n} sin(x[src_e]).
//
// History: R1 global atomics 634us (400MB of 32B atomic write-through).
// R2 LDS-privatized rescan 200us — latency-chain-bound: gather+atomic in the
// same branch body => 4 serialized L2 round-trips/iter; grid 512 = 2 blk/CU.
// R3 unconditional atomics: 16x LDS-atomic inflation => 2ms. REGRESSION.
// R4: conditional gathers/atomics (total = E, not NPART*E), but all 4 gathers
// issued into regs BEFORE the atomic blocks (one vmcnt drain per 4 edges),
// grid 768 = 3 blk/CU (24 waves/CU), per-slice count rounded to x4 so the
// int4 path always applies.

#define EPS 1e-12f
#define NPART 16
#define RMAX 6250      // ceil(100000/16) -> 50KB LDS -> 3 blocks/CU
#define BLK 512

// ---------------- fast path ----------------

__global__ void build_cs_kernel(const float* __restrict__ x,
                                float2* __restrict__ cst, int N) {
    int i = blockIdx.x * blockDim.x + threadIdx.x;
    if (i < N) {
        float sn, cs;
        __sincosf(x[i], &sn, &cs);
        cst[i] = make_float2(cs, sn);
    }
}

__global__ __launch_bounds__(BLK, 6) void scatter_lds_kernel(
        const float2* __restrict__ cst,
        const int* __restrict__ esrc,
        const int* __restrict__ edst,
        float* __restrict__ buf,       // [NPART*nslice][2*R]
        int E, int R, int nslice) {
    __shared__ float lacc[2 * RMAX];   // [0,R)=C, [R,2R)=S
    const int p = blockIdx.x / nslice;
    const int s = blockIdx.x % nslice;
    const int pBeg = p * R;

    for (int k = threadIdx.x; k < 2 * R; k += BLK) lacc[k] = 0.0f;
    __syncthreads();

    // per-slice edge count rounded to x4 so beg is always 16B-aligned
    const int per = (((E + nslice - 1) / nslice) + 3) & ~3;
    const int beg = s * per;
    const int end = min(beg + per, E);
    const int end4 = beg + (max(end - beg, 0) & ~3);

    for (int i = beg + threadIdx.x * 4; i < end4; i += BLK * 4) {
        const int4 d4 = *(const int4*)&edst[i];
        const int4 s4 = *(const int4*)&esrc[i];
        const unsigned dl0 = (unsigned)(d4.x - pBeg);
        const unsigned dl1 = (unsigned)(d4.y - pBeg);
        const unsigned dl2 = (unsigned)(d4.z - pBeg);
        const unsigned dl3 = (unsigned)(d4.w - pBeg);
        const bool h0 = dl0 < (unsigned)R;
        const bool h1 = dl1 < (unsigned)R;
        const bool h2 = dl2 < (unsigned)R;
        const bool h3 = dl3 < (unsigned)R;
        // issue ALL conditional gathers first: loads pipeline, one drain,
        // miss lanes skip via execz (no wasted L2 requests)
        float2 v0 = make_float2(0.f, 0.f), v1 = v0, v2 = v0, v3 = v0;
        if (h0) v0 = cst[s4.x];
        if (h1) v1 = cst[s4.y];
        if (h2) v2 = cst[s4.z];
        if (h3) v3 = cst[s4.w];
        // then the conditional LDS atomics (total 2E across whole grid)
        if (h0) { atomicAdd(&lacc[dl0], v0.x); atomicAdd(&lacc[dl0 + R], v0.y); }
        if (h1) { atomicAdd(&lacc[dl1], v1.x); atomicAdd(&lacc[dl1 + R], v1.y); }
        if (h2) { atomicAdd(&lacc[dl2], v2.x); atomicAdd(&lacc[dl2 + R], v2.y); }
        if (h3) { atomicAdd(&lacc[dl3], v3.x); atomicAdd(&lacc[dl3 + R], v3.y); }
    }
    for (int i = end4 + threadIdx.x; i < end; i += BLK) {
        unsigned dl = (unsigned)(edst[i] - pBeg);
        if (dl < (unsigned)R) {
            float2 v = cst[esrc[i]];
            atomicAdd(&lacc[dl], v.x);
            atomicAdd(&lacc[dl + R], v.y);
        }
    }

    __syncthreads();
    float* dst = buf + (size_t)blockIdx.x * (2 * R);
    for (int k = threadIdx.x; k < 2 * R; k += BLK) dst[k] = lacc[k];
}

__global__ void reduce_node_kernel(const float* __restrict__ theta,
                                   const float* __restrict__ buf,
                                   float* __restrict__ out, int N, int R,
                                   int nslice) {
    int n = blockIdx.x * blockDim.x + threadIdx.x;
    if (n >= N) return;
    int p = n / R, j = n - p * R;
    float C = 0.0f, Sv = 0.0f;
    size_t base = (size_t)p * nslice * 2 * R + j;
    #pragma unroll 8
    for (int s = 0; s < nslice; ++s) {
        const float* b = buf + base + (size_t)s * 2 * R;
        C  += b[0];
        Sv += b[R];
    }
    float sn, cs;
    __sincosf(theta[n], &sn, &cs);
    float nrm = fmaxf(sqrtf(C * C + Sv * Sv), EPS);
    out[3 * n + 0] = cs;
    out[3 * n + 1] = sn;
    out[3 * n + 2] = (cs * Sv - sn * C) / nrm;
}

// ---------------- fallback path (R1: global atomics) ----------------

__global__ void zero_kernel(float* __restrict__ p, int n) {
    int i = blockIdx.x * blockDim.x + threadIdx.x;
    if (i < n) p[i] = 0.0f;
}

__global__ void edge_atomic_kernel(const float* __restrict__ x,
                                   const float* __restrict__ theta,
                                   const int* __restrict__ esrc,
                                   const int* __restrict__ edst,
                                   float* __restrict__ acc, int E) {
    int i = blockIdx.x * blockDim.x + threadIdx.x;
    if (i >= E) return;
    int s = esrc[i], d = edst[i];
    float dt = x[s] - theta[d];
    float sn, cs;
    __sincosf(dt, &sn, &cs);
    atomicAdd(&acc[2 * d], cs);
    atomicAdd(&acc[2 * d + 1], sn);
}

__global__ void node_atomic_kernel(const float* __restrict__ theta,
                                   const float* __restrict__ acc,
                                   float* __restrict__ out, int N) {
    int n = blockIdx.x * blockDim.x + threadIdx.x;
    if (n >= N) return;
    float sn, cs;
    __sincosf(theta[n], &sn, &cs);
    float sx = acc[2 * n], sy = acc[2 * n + 1];
    float nrm = fmaxf(sqrtf(sx * sx + sy * sy), EPS);
    out[3 * n + 0] = cs;
    out[3 * n + 1] = sn;
    out[3 * n + 2] = sy / nrm;
}

extern "C" void kernel_launch(void* const* d_in, const int* in_sizes, int n_in,
                              void* d_out, int out_size, void* d_ws, size_t ws_size,
                              hipStream_t stream) {
    const float* x     = (const float*)d_in[0];
    const float* theta = (const float*)d_in[1];
    const int*   esrc  = (const int*)d_in[2];
    const int*   edst  = (const int*)d_in[3];
    float*       out   = (float*)d_out;

    int N = in_sizes[0];
    int E = in_sizes[2];
    int R = (N + NPART - 1) / NPART;

    size_t cst_bytes = (size_t)N * sizeof(float2);

    // pick largest nslice whose partial buffer fits in ws
    int nslice = 0;
    for (int cand : {48, 32, 16}) {
        size_t need = (size_t)NPART * cand * 2 * R * sizeof(float) + cst_bytes;
        if (ws_size >= need) { nslice = cand; break; }
    }

    if (R <= RMAX && nslice > 0) {
        size_t buf_bytes = (size_t)NPART * nslice * 2 * R * sizeof(float);
        float*  buf = (float*)d_ws;
        float2* cst = (float2*)((char*)d_ws + buf_bytes);
        build_cs_kernel<<<(N + 255) / 256, 256, 0, stream>>>(x, cst, N);
        scatter_lds_kernel<<<NPART * nslice, BLK, 0, stream>>>(cst, esrc, edst, buf, E, R, nslice);
        reduce_node_kernel<<<(N + 255) / 256, 256, 0, stream>>>(theta, buf, out, N, R, nslice);
    } else {
        float* acc = (float*)d_ws;
        const int B = 256;
        zero_kernel<<<(2 * N + B - 1) / B, B, 0, stream>>>(acc, 2 * N);
        edge_atomic_kernel<<<(E + B - 1) / B, B, 0, stream>>>(x, theta, esrc, edst, acc, E);
        node_atomic_kernel<<<(N + B - 1) / B, B, 0, stream>>>(theta, acc, out, N);
    }
}

// Round 5
// 196.603 us; speedup vs baseline: 10.7450x; 1.0132x over previous
//
#include <hip/hip_runtime.h>
#include <math.h>

// N=100000 nodes, E=6400000 edges, avg degree 64.
// out[n] = [cos(th_n), sin(th_n), w_n],  w_n = S_y / max(||S||, eps),
//   S_x = cos(th)*C + sin(th)*S,  S_y = cos(th)*S - sin(th)*C,
//   C_n = sum_{e:dst=n} cos(x[src_e]),  S_n = sum_{e:dst=n} sin(x[src_e]).
//
// History: R1 global atomics 634us (32B atomic write-through x 12.8M).
// R2 LDS-partition rescan 200us (latency chains). R3 unconditional atomics
// 2ms REGRESSION (16x LDS-atomic inflation). R4 pipelined conditional scan
// 199us total / 118us scatter — L3-BW-bound on the 16x edge rescan (~820MB
// through L3; FETCH only 28MB). R5: unstable counting sort. Phase 1 reads
// edges ONCE, packs (src<<13)|dst_local into per-partition buckets (exact
// slots: LDS histogram -> 1 global atomic per block*partition -> LDS cursor).
// Phase 2 streams buckets (100% hit rate), gathers float2 cst[src] from L2,
// LDS-accumulates, flushes partials; reduce fuses epilogue. Edge traffic
// ~130MB total instead of 820MB.

#define EPS 1e-12f
#define NPART 16
#define RMAX 6250      // ceil(100000/16): 2R floats = 50KB LDS
#define BLK1 256
#define CH   8192      // edges per phase-1 block
#define BLK2 512

// ---------------- common ----------------

__global__ void build_cs_kernel(const float* __restrict__ x,
                                float2* __restrict__ cst,
                                int* __restrict__ gcount, int N) {
    int i = blockIdx.x * blockDim.x + threadIdx.x;
    if (blockIdx.x == 0 && threadIdx.x < NPART) gcount[threadIdx.x] = 0;
    if (i < N) {
        float sn, cs;
        __sincosf(x[i], &sn, &cs);
        cst[i] = make_float2(cs, sn);
    }
}

// ---------------- R5 fast path: counting sort ----------------

__global__ __launch_bounds__(BLK1) void phase1_bucket_kernel(
        const int* __restrict__ esrc,
        const int* __restrict__ edst,
        unsigned* __restrict__ bucket,   // NPART regions of CAP entries
        int* __restrict__ gcount,
        int E, int R, unsigned inv32, int cap) {
    __shared__ int hist[NPART];
    __shared__ int cursor[NPART];
    if (threadIdx.x < NPART) hist[threadIdx.x] = 0;
    __syncthreads();

    const int beg = blockIdx.x * CH;
    const int end = min(beg + CH, E);
    const int end4 = beg + (max(end - beg, 0) & ~3);

    // pass A: per-block partition histogram
    for (int i = beg + threadIdx.x * 4; i < end4; i += BLK1 * 4) {
        const int4 d4 = *(const int4*)&edst[i];
        atomicAdd(&hist[__umulhi((unsigned)d4.x, inv32)], 1);
        atomicAdd(&hist[__umulhi((unsigned)d4.y, inv32)], 1);
        atomicAdd(&hist[__umulhi((unsigned)d4.z, inv32)], 1);
        atomicAdd(&hist[__umulhi((unsigned)d4.w, inv32)], 1);
    }
    for (int i = end4 + threadIdx.x; i < end; i += BLK1)
        atomicAdd(&hist[__umulhi((unsigned)edst[i], inv32)], 1);
    __syncthreads();

    // reserve contiguous slot ranges per partition
    if (threadIdx.x < NPART) {
        int base = atomicAdd(&gcount[threadIdx.x], hist[threadIdx.x]);
        cursor[threadIdx.x] = threadIdx.x * cap + base;
    }
    __syncthreads();

    // pass B: re-read (L2-warm) and scatter packed entries
    for (int i = beg + threadIdx.x * 4; i < end4; i += BLK1 * 4) {
        const int4 d4 = *(const int4*)&edst[i];
        const int4 s4 = *(const int4*)&esrc[i];
        {   unsigned p = __umulhi((unsigned)d4.x, inv32);
            unsigned l = (unsigned)d4.x - p * R;
            int slot = atomicAdd(&cursor[p], 1);
            if (slot < (int)(p + 1) * cap) bucket[slot] = ((unsigned)s4.x << 13) | l; }
        {   unsigned p = __umulhi((unsigned)d4.y, inv32);
            unsigned l = (unsigned)d4.y - p * R;
            int slot = atomicAdd(&cursor[p], 1);
            if (slot < (int)(p + 1) * cap) bucket[slot] = ((unsigned)s4.y << 13) | l; }
        {   unsigned p = __umulhi((unsigned)d4.z, inv32);
            unsigned l = (unsigned)d4.z - p * R;
            int slot = atomicAdd(&cursor[p], 1);
            if (slot < (int)(p + 1) * cap) bucket[slot] = ((unsigned)s4.z << 13) | l; }
        {   unsigned p = __umulhi((unsigned)d4.w, inv32);
            unsigned l = (unsigned)d4.w - p * R;
            int slot = atomicAdd(&cursor[p], 1);
            if (slot < (int)(p + 1) * cap) bucket[slot] = ((unsigned)s4.w << 13) | l; }
    }
    for (int i = end4 + threadIdx.x; i < end; i += BLK1) {
        int d = edst[i];
        unsigned p = __umulhi((unsigned)d, inv32);
        unsigned l = (unsigned)d - p * R;
        int slot = atomicAdd(&cursor[p], 1);
        if (slot < (int)(p + 1) * cap) bucket[slot] = ((unsigned)esrc[i] << 13) | l;
    }
}

__global__ __launch_bounds__(BLK2) void phase2_accum_kernel(
        const unsigned* __restrict__ bucket,
        const float2* __restrict__ cst,
        const int* __restrict__ gcount,
        float* __restrict__ partials,    // [NPART*SL][2*R]
        int R, int cap, int SL) {
    __shared__ float lacc[2 * RMAX];
    const int p = blockIdx.x / SL;
    const int s = blockIdx.x % SL;

    for (int k = threadIdx.x; k < 2 * R; k += BLK2) lacc[k] = 0.0f;
    __syncthreads();

    const int cnt = min(gcount[p], cap);
    const int per = (((cnt + SL - 1) / SL) + 3) & ~3;
    const unsigned* bk = bucket + (size_t)p * cap;
    const int beg = s * per;
    const int end = min(beg + per, cnt);
    const int end4 = beg + (max(end - beg, 0) & ~3);

    for (int i = beg + threadIdx.x * 4; i < end4; i += BLK2 * 4) {
        const uint4 e4 = *(const uint4*)&bk[i];
        const unsigned l0 = e4.x & 8191u, l1 = e4.y & 8191u;
        const unsigned l2 = e4.z & 8191u, l3 = e4.w & 8191u;
        // 4 independent gathers issued before any atomic: one drain per group
        const float2 v0 = cst[e4.x >> 13];
        const float2 v1 = cst[e4.y >> 13];
        const float2 v2 = cst[e4.z >> 13];
        const float2 v3 = cst[e4.w >> 13];
        atomicAdd(&lacc[l0], v0.x); atomicAdd(&lacc[l0 + R], v0.y);
        atomicAdd(&lacc[l1], v1.x); atomicAdd(&lacc[l1 + R], v1.y);
        atomicAdd(&lacc[l2], v2.x); atomicAdd(&lacc[l2 + R], v2.y);
        atomicAdd(&lacc[l3], v3.x); atomicAdd(&lacc[l3 + R], v3.y);
    }
    for (int i = end4 + threadIdx.x; i < end; i += BLK2) {
        const unsigned e = bk[i];
        const unsigned l = e & 8191u;
        const float2 v = cst[e >> 13];
        atomicAdd(&lacc[l], v.x); atomicAdd(&lacc[l + R], v.y);
    }

    __syncthreads();
    float* dst = partials + (size_t)blockIdx.x * (2 * R);
    for (int k = threadIdx.x; k < 2 * R; k += BLK2) dst[k] = lacc[k];
}

__global__ void reduce_node_kernel(const float* __restrict__ theta,
                                   const float* __restrict__ buf,
                                   float* __restrict__ out, int N, int R,
                                   int nslice) {
    int n = blockIdx.x * blockDim.x + threadIdx.x;
    if (n >= N) return;
    int p = n / R, j = n - p * R;
    float C = 0.0f, Sv = 0.0f;
    size_t base = (size_t)p * nslice * 2 * R + j;
    #pragma unroll 8
    for (int s = 0; s < nslice; ++s) {
        const float* b = buf + base + (size_t)s * 2 * R;
        C  += b[0];
        Sv += b[R];
    }
    float sn, cs;
    __sincosf(theta[n], &sn, &cs);
    float nrm = fmaxf(sqrtf(C * C + Sv * Sv), EPS);
    out[3 * n + 0] = cs;
    out[3 * n + 1] = sn;
    out[3 * n + 2] = (cs * Sv - sn * C) / nrm;
}

// ---------------- R4 fallback: pipelined conditional rescan ----------------

__global__ void build_cs_only_kernel(const float* __restrict__ x,
                                     float2* __restrict__ cst, int N) {
    int i = blockIdx.x * blockDim.x + threadIdx.x;
    if (i < N) {
        float sn, cs;
        __sincosf(x[i], &sn, &cs);
        cst[i] = make_float2(cs, sn);
    }
}

__global__ __launch_bounds__(512, 6) void scatter_lds_kernel(
        const float2* __restrict__ cst,
        const int* __restrict__ esrc,
        const int* __restrict__ edst,
        float* __restrict__ buf, int E, int R, int nslice) {
    __shared__ float lacc[2 * RMAX];
    const int p = blockIdx.x / nslice;
    const int s = blockIdx.x % nslice;
    const int pBeg = p * R;
    for (int k = threadIdx.x; k < 2 * R; k += 512) lacc[k] = 0.0f;
    __syncthreads();
    const int per = (((E + nslice - 1) / nslice) + 3) & ~3;
    const int beg = s * per;
    const int end = min(beg + per, E);
    const int end4 = beg + (max(end - beg, 0) & ~3);
    for (int i = beg + threadIdx.x * 4; i < end4; i += 512 * 4) {
        const int4 d4 = *(const int4*)&edst[i];
        const int4 s4 = *(const int4*)&esrc[i];
        const unsigned dl0 = (unsigned)(d4.x - pBeg);
        const unsigned dl1 = (unsigned)(d4.y - pBeg);
        const unsigned dl2 = (unsigned)(d4.z - pBeg);
        const unsigned dl3 = (unsigned)(d4.w - pBeg);
        const bool h0 = dl0 < (unsigned)R, h1 = dl1 < (unsigned)R;
        const bool h2 = dl2 < (unsigned)R, h3 = dl3 < (unsigned)R;
        float2 v0 = make_float2(0.f, 0.f), v1 = v0, v2 = v0, v3 = v0;
        if (h0) v0 = cst[s4.x];
        if (h1) v1 = cst[s4.y];
        if (h2) v2 = cst[s4.z];
        if (h3) v3 = cst[s4.w];
        if (h0) { atomicAdd(&lacc[dl0], v0.x); atomicAdd(&lacc[dl0 + R], v0.y); }
        if (h1) { atomicAdd(&lacc[dl1], v1.x); atomicAdd(&lacc[dl1 + R], v1.y); }
        if (h2) { atomicAdd(&lacc[dl2], v2.x); atomicAdd(&lacc[dl2 + R], v2.y); }
        if (h3) { atomicAdd(&lacc[dl3], v3.x); atomicAdd(&lacc[dl3 + R], v3.y); }
    }
    for (int i = end4 + threadIdx.x; i < end; i += 512) {
        unsigned dl = (unsigned)(edst[i] - pBeg);
        if (dl < (unsigned)R) {
            float2 v = cst[esrc[i]];
            atomicAdd(&lacc[dl], v.x);
            atomicAdd(&lacc[dl + R], v.y);
        }
    }
    __syncthreads();
    float* dst = buf + (size_t)blockIdx.x * (2 * R);
    for (int k = threadIdx.x; k < 2 * R; k += 512) dst[k] = lacc[k];
}

// ---------------- R1 fallback: global atomics ----------------

__global__ void zero_kernel(float* __restrict__ p, int n) {
    int i = blockIdx.x * blockDim.x + threadIdx.x;
    if (i < n) p[i] = 0.0f;
}

__global__ void edge_atomic_kernel(const float* __restrict__ x,
                                   const float* __restrict__ theta,
                                   const int* __restrict__ esrc,
                                   const int* __restrict__ edst,
                                   float* __restrict__ acc, int E) {
    int i = blockIdx.x * blockDim.x + threadIdx.x;
    if (i >= E) return;
    int s = esrc[i], d = edst[i];
    float dt = x[s] - theta[d];
    float sn, cs;
    __sincosf(dt, &sn, &cs);
    atomicAdd(&acc[2 * d], cs);
    atomicAdd(&acc[2 * d + 1], sn);
}

__global__ void node_atomic_kernel(const float* __restrict__ theta,
                                   const float* __restrict__ acc,
                                   float* __restrict__ out, int N) {
    int n = blockIdx.x * blockDim.x + threadIdx.x;
    if (n >= N) return;
    float sn, cs;
    __sincosf(theta[n], &sn, &cs);
    float sx = acc[2 * n], sy = acc[2 * n + 1];
    float nrm = fmaxf(sqrtf(sx * sx + sy * sy), EPS);
    out[3 * n + 0] = cs;
    out[3 * n + 1] = sn;
    out[3 * n + 2] = sy / nrm;
}

extern "C" void kernel_launch(void* const* d_in, const int* in_sizes, int n_in,
                              void* d_out, int out_size, void* d_ws, size_t ws_size,
                              hipStream_t stream) {
    const float* x     = (const float*)d_in[0];
    const float* theta = (const float*)d_in[1];
    const int*   esrc  = (const int*)d_in[2];
    const int*   edst  = (const int*)d_in[3];
    float*       out   = (float*)d_out;

    const int N = in_sizes[0];
    const int E = in_sizes[2];
    const int R = (N + NPART - 1) / NPART;

    // magic inverse for part = dst / R via umulhi
    unsigned long long inv64 = (0x100000000ULL + (unsigned)R - 1) / (unsigned)R;
    unsigned long long merr  = inv64 * (unsigned)R - 0x100000000ULL;
    bool magic_ok = (inv64 < 0x100000000ULL) &&
                    (merr * (unsigned long long)(N > 0 ? N - 1 : 0) < 0x100000000ULL);

    const int cap = (((E + NPART - 1) / NPART) + 8192 + 3) & ~3;  // +13 sigma slack
    const size_t bucket_bytes = (size_t)NPART * cap * sizeof(unsigned);
    const size_t cst_bytes    = (size_t)N * sizeof(float2);
    const size_t gcount_bytes = 256;

    int SL = 0;
    for (int cand : {32, 16, 8}) {
        size_t need = bucket_bytes + (size_t)NPART * cand * 2 * R * sizeof(float)
                      + cst_bytes + gcount_bytes;
        if (ws_size >= need) { SL = cand; break; }
    }

    const bool pack_ok = (R <= 8191) && ((long long)N <= (1LL << 17)) && magic_ok;

    if (R <= RMAX && pack_ok && SL > 0) {
        // layout: [buckets][partials][cst][gcount]
        const size_t partial_bytes = (size_t)NPART * SL * 2 * R * sizeof(float);
        unsigned* bucket   = (unsigned*)d_ws;
        float*    partials = (float*)((char*)d_ws + bucket_bytes);
        float2*   cst      = (float2*)((char*)d_ws + bucket_bytes + partial_bytes);
        int*      gcount   = (int*)((char*)d_ws + bucket_bytes + partial_bytes + cst_bytes);

        build_cs_kernel<<<(N + 255) / 256, 256, 0, stream>>>(x, cst, gcount, N);
        phase1_bucket_kernel<<<(E + CH - 1) / CH, BLK1, 0, stream>>>(
            esrc, edst, bucket, gcount, E, R, (unsigned)inv64, cap);
        phase2_accum_kernel<<<NPART * SL, BLK2, 0, stream>>>(
            bucket, cst, gcount, partials, R, cap, SL);
        reduce_node_kernel<<<(N + 255) / 256, 256, 0, stream>>>(
            theta, partials, out, N, R, SL);
        return;
    }

    // R4 fallback
    int nslice = 0;
    for (int cand : {48, 32, 16}) {
        size_t need = (size_t)NPART * cand * 2 * R * sizeof(float) + cst_bytes;
        if (ws_size >= need) { nslice = cand; break; }
    }
    if (R <= RMAX && nslice > 0) {
        size_t buf_bytes = (size_t)NPART * nslice * 2 * R * sizeof(float);
        float*  buf = (float*)d_ws;
        float2* cst = (float2*)((char*)d_ws + buf_bytes);
        build_cs_only_kernel<<<(N + 255) / 256, 256, 0, stream>>>(x, cst, N);
        scatter_lds_kernel<<<NPART * nslice, 512, 0, stream>>>(cst, esrc, edst, buf, E, R, nslice);
        reduce_node_kernel<<<(N + 255) / 256, 256, 0, stream>>>(theta, buf, out, N, R, nslice);
    } else {
        float* acc = (float*)d_ws;
        const int B = 256;
        zero_kernel<<<(2 * N + B - 1) / B, B, 0, stream>>>(acc, 2 * N);
        edge_atomic_kernel<<<(E + B - 1) / B, B, 0, stream>>>(x, theta, esrc, edst, acc, E);
        node_atomic_kernel<<<(N + B - 1) / B, B, 0, stream>>>(theta, acc, out, N);
    }
}